// Round 2
// baseline (314.405 us; speedup 1.0000x reference)
//
#include <hip/hip_runtime.h>
#include <stdint.h>

typedef unsigned short u16;
typedef unsigned int u32;

typedef __bf16 bf8 __attribute__((ext_vector_type(8)));
typedef bf8 bf8a __attribute__((may_alias));
typedef float f32x4 __attribute__((ext_vector_type(4)));
typedef uint2 uint2a __attribute__((may_alias));
typedef ushort4 ushort4a __attribute__((may_alias));
typedef float4 float4a __attribute__((may_alias));

#define MFMA_BF16(a, b, c) __builtin_amdgcn_mfma_f32_16x16x32_bf16((a), (b), (c), 0, 0, 0)

__device__ __forceinline__ u16 f2b(float x) {
  u32 u = __float_as_uint(x);
  return (u16)((u + 0x7fffu + ((u >> 16) & 1u)) >> 16);  // RNE
}
__device__ __forceinline__ u32 pack2(float a, float b) {  // two f32 -> packed bf16x2 (sign-preserving)
  u32 ua = __float_as_uint(a), ub = __float_as_uint(b);
  return ((ua + 0x8000u) >> 16) | ((ub + 0x8000u) & 0xffff0000u);
}
__device__ __forceinline__ void async16(const u16* g, void* l) {
  __builtin_amdgcn_global_load_lds((const __attribute__((address_space(1))) u32*)g,
                                   (__attribute__((address_space(3))) u32*)l, 16, 0, 0);
}

// ---------------------------------------------------------------------------
// src convert: fp32 [4096][1024] -> bf16 same layout. 1 float4 per thread.
// ---------------------------------------------------------------------------
__global__ __launch_bounds__(256) void convert_src(const float* __restrict__ src,
                                                   u16* __restrict__ dst) {
  const int i = blockIdx.x * 256 + threadIdx.x;  // float4 index
  float4 v = *(const float4a*)(src + i * 4);
  ushort4 o;
  o.x = f2b(v.x); o.y = f2b(v.y); o.z = f2b(v.z); o.w = f2b(v.w);
  *(ushort4a*)(dst + i * 4) = o;
}

// ---------------------------------------------------------------------------
// EB precompute: fp32 [2048][2048] -> bf16 sign(b)*exp(b), 16x16-tiled layout:
// E2[(s>>4)*128 + (t>>4)][ (s&15)*16 + (t&15) ]  (256 elem = 512 B per tile)
// A wave's (st,tt) fragment read becomes one contiguous 512 B tile.
// ---------------------------------------------------------------------------
__global__ __launch_bounds__(256) void prep_eb(const float* __restrict__ EB,
                                               u16* __restrict__ E2) {
  const int gid = blockIdx.x * 256 + threadIdx.x;
  const int s = gid >> 9;            // 512 float4 per row
  const int t = (gid & 511) * 4;
  const float4 v = *(const float4a*)(EB + s * 2048 + t);
  const float c2 = 1.44269504088896340736f;  // log2(e)
  ushort4 o;
  o.x = f2b(__builtin_amdgcn_exp2f(v.x * c2)) | (u16)((__float_as_uint(v.x) >> 16) & 0x8000u);
  o.y = f2b(__builtin_amdgcn_exp2f(v.y * c2)) | (u16)((__float_as_uint(v.y) >> 16) & 0x8000u);
  o.z = f2b(__builtin_amdgcn_exp2f(v.z * c2)) | (u16)((__float_as_uint(v.z) >> 16) & 0x8000u);
  o.w = f2b(__builtin_amdgcn_exp2f(v.w * c2)) | (u16)((__float_as_uint(v.w) >> 16) & 0x8000u);
  const int ti = ((s >> 4) * 128 + (t >> 4)) * 256 + (s & 15) * 16 + (t & 15);
  *(ushort4a*)(E2 + ti) = o;
}

// ---------------------------------------------------------------------------
// Weight transpose+convert: w fp32 [K=1024][N=1024] -> wT bf16 [N][K]
// ---------------------------------------------------------------------------
__global__ __launch_bounds__(256) void transpose4(
    const float* __restrict__ w0, const float* __restrict__ w1,
    const float* __restrict__ w2, const float* __restrict__ w3,
    u16* __restrict__ t0, u16* __restrict__ t1, u16* __restrict__ t2, u16* __restrict__ t3) {
  const int z = blockIdx.z;
  const float* W = z == 0 ? w0 : z == 1 ? w1 : z == 2 ? w2 : w3;
  u16* T = z == 0 ? t0 : z == 1 ? t1 : z == 2 ? t2 : t3;
  __shared__ __align__(8) u16 tile[64][68];
  const int tid = threadIdx.x;
  const int ty = tid >> 4, tx = tid & 15;
  const int kb = blockIdx.y * 64, nb = blockIdx.x * 64;
#pragma unroll
  for (int i = 0; i < 4; ++i) {
    int lk = ty + i * 16;
    float4 v = *(const float4a*)(W + (kb + lk) * 1024 + nb + tx * 4);
    ushort4 h;
    h.x = f2b(v.x); h.y = f2b(v.y); h.z = f2b(v.z); h.w = f2b(v.w);
    *(ushort4a*)&tile[lk][tx * 4] = h;
  }
  __syncthreads();
#pragma unroll
  for (int i = 0; i < 4; ++i) {
    int ln = ty + i * 16;
    ushort4 v;
    v.x = tile[tx * 4 + 0][ln];
    v.y = tile[tx * 4 + 1][ln];
    v.z = tile[tx * 4 + 2][ln];
    v.w = tile[tx * 4 + 3][ln];
    *(ushort4a*)(T + (nb + ln) * 1024 + kb + tx * 4) = v;
  }
}

// ---------------------------------------------------------------------------
// GEMM: C[M][N] = A[M,1024] * Bt[N,1024]^T + bias[n]   (m97 structure)
// ---------------------------------------------------------------------------
__global__ __launch_bounds__(256) void gemm_bt(
    const u16* __restrict__ A,
    const u16* __restrict__ B0, const u16* __restrict__ B1, const u16* __restrict__ B2,
    const float* __restrict__ c0, const float* __restrict__ c1, const float* __restrict__ c2,
    u16* __restrict__ O0, u16* __restrict__ O1, u16* __restrict__ O2,
    float* __restrict__ Of, int plain) {
  __shared__ __align__(16) u16 sm[8192];
  u16* As = sm;
  u16* Bs = sm + 4096;
  const int tid = threadIdx.x, lane = tid & 63, w = tid >> 6;
  const int wm = w >> 1, wn = w & 1, quad = lane >> 4, l16 = lane & 15;
  const int z = blockIdx.z;
  const u16* Bt = z == 0 ? B0 : (z == 1 ? B1 : B2);
  const float* bi = z == 0 ? c0 : (z == 1 ? c1 : c2);
  u16* O = z == 0 ? O0 : (z == 1 ? O1 : O2);
  const int row0 = blockIdx.y * 128, col0 = blockIdx.x * 128;

  f32x4 acc[4][4];
#pragma unroll
  for (int i = 0; i < 4; ++i)
#pragma unroll
    for (int j = 0; j < 4; ++j) acc[i][j] = f32x4{0.f, 0.f, 0.f, 0.f};

  const int e0 = tid, e1 = tid + 256;
  const int r0 = e0 >> 2, cc0 = (e0 & 3) * 8;
  const int r1 = e1 >> 2, cc1 = (e1 & 3) * 8;
  const u32 lb0 = (u32)(w * 64) * 16;
  const u32 lb1 = (u32)(w * 64 + 256) * 16;

  for (int k0 = 0; k0 < 1024; k0 += 32) {
    __syncthreads();
    async16(A + (row0 + r0) * 1024 + k0 + cc0, (char*)As + lb0);
    async16(A + (row0 + r1) * 1024 + k0 + cc1, (char*)As + lb1);
    async16(Bt + (col0 + r0) * 1024 + k0 + cc0, (char*)Bs + lb0);
    async16(Bt + (col0 + r1) * 1024 + k0 + cc1, (char*)Bs + lb1);
    __syncthreads();
    bf8a af[4], bfr[4];
#pragma unroll
    for (int i = 0; i < 4; ++i) {
      af[i] = *(const bf8a*)(As + (wm * 64 + i * 16 + l16) * 32 + quad * 8);
      bfr[i] = *(const bf8a*)(Bs + (wn * 64 + i * 16 + l16) * 32 + quad * 8);
    }
#pragma unroll
    for (int mt = 0; mt < 4; ++mt)
#pragma unroll
      for (int nt = 0; nt < 4; ++nt) acc[mt][nt] = MFMA_BF16(af[mt], bfr[nt], acc[mt][nt]);
  }

#pragma unroll
  for (int nt = 0; nt < 4; ++nt) {
    const int col = col0 + wn * 64 + nt * 16 + l16;
    const float bcol = bi[col];
#pragma unroll
    for (int mt = 0; mt < 4; ++mt) {
#pragma unroll
      for (int r = 0; r < 4; ++r) {
        const int rm = row0 + wm * 64 + mt * 16 + quad * 4 + r;
        const float fv = acc[mt][nt][r] + bcol;
        if (plain) {
          Of[rm * 1024 + col] = fv;
        } else {
          const u16 hv = f2b(fv);
          const int s = rm >> 1, b_ = rm & 1, hh = col >> 6, e = col & 63;
          const int p = b_ * 16 + hh;
          if (z < 2) O[(p * 2048 + s) * 64 + e] = hv;  // [pair][s][64]
          else O[(p * 64 + e) * 2048 + s] = hv;        // [pair][e][s] (V^T)
        }
      }
    }
  }
}

// ---------------------------------------------------------------------------
// Flash attention v10 = v9 + ENFORCED software pipeline:
//  - sched_barrier(0) fences pin the prefetch issue points (v9's VGPR=68
//    proved the compiler sank the "prefetched" loads to their consumers,
//    exposing full L2/L3 latency every stage)
//  - K+EB prefetched one full stage ahead (double-buffered registers)
//  - V issued at COMPUTE top, consumed at bottom (S-MFMA + exp covers it)
//  - s_setprio(1) around MFMA clusters (T5; waves are barrier-free/desynced)
// ---------------------------------------------------------------------------
#define PREFETCH_KE(kf, eb, kt_)                                                    \
  {                                                                                 \
    const int tb_ = (kt_) * 128 + w * 32;                                           \
    _Pragma("unroll") for (int tt = 0; tt < 2; ++tt) {                              \
      const u16* kr_ = Kp + (tb_ + tt * 16 + l16) * 64 + quad * 8;                  \
      kf[tt][0] = *(const bf8a*)kr_;                                                \
      kf[tt][1] = *(const bf8a*)(kr_ + 32);                                         \
    }                                                                               \
    const int tb16_ = (kt_) * 8 + w * 2;                                            \
    _Pragma("unroll") for (int st = 0; st < 2; ++st)                                \
      _Pragma("unroll") for (int tt = 0; tt < 2; ++tt)                              \
        eb[st][tt] = *(const uint2a*)(EBp + ((qt * 2 + st) * 128 + tb16_ + tt) * 256 \
                                      + l16 * 16 + quad * 4);                       \
  }

#define COMPUTE(kf, eb, Pp, kt_)                                                    \
  {                                                                                 \
    const int tb_ = (kt_) * 128 + w * 32;                                           \
    bf8a vf[4];                                                                     \
    _Pragma("unroll") for (int nt = 0; nt < 4; ++nt)                                \
      vf[nt] = *(const bf8a*)(Vp + (nt * 16 + l16) * 2048 + tb_ + quad * 8);        \
    __builtin_amdgcn_sched_barrier(0); /* V issue pinned before S-phase */          \
    f32x4 sacc[2][2];                                                               \
    __builtin_amdgcn_s_setprio(1);                                                  \
    _Pragma("unroll") for (int tt = 0; tt < 2; ++tt)                                \
      _Pragma("unroll") for (int st = 0; st < 2; ++st) {                            \
        f32x4 t0_ = f32x4{0.f, 0.f, 0.f, 0.f};                                      \
        t0_ = MFMA_BF16(kf[tt][0], qf[st][0], t0_);                                 \
        sacc[tt][st] = MFMA_BF16(kf[tt][1], qf[st][1], t0_);                        \
      }                                                                             \
    __builtin_amdgcn_s_setprio(0);                                                  \
    _Pragma("unroll") for (int st = 0; st < 2; ++st) {                              \
      _Pragma("unroll") for (int tt = 0; tt < 2; ++tt) {                            \
        const uint2 e_ = eb[st][tt];                                                \
        const float g0 = __uint_as_float(e_.x << 16);                               \
        const float g1 = __uint_as_float(e_.x & 0xffff0000u);                       \
        const float g2 = __uint_as_float(e_.y << 16);                               \
        const float g3 = __uint_as_float(e_.y & 0xffff0000u);                       \
        const float p0 = __builtin_amdgcn_exp2f(sacc[tt][st][0] * c1) * g0;         \
        const float p1 = __builtin_amdgcn_exp2f(sacc[tt][st][1] * c1) * g1;         \
        const float p2 = __builtin_amdgcn_exp2f(sacc[tt][st][2] * c1) * g2;         \
        const float p3 = __builtin_amdgcn_exp2f(sacc[tt][st][3] * c1) * g3;         \
        lsum[st] += (__builtin_fabsf(p0) + __builtin_fabsf(p1)) +                   \
                    (__builtin_fabsf(p2) + __builtin_fabsf(p3));                    \
        uint2 v_;                                                                   \
        v_.x = pack2(p0, p1);                                                       \
        v_.y = pack2(p2, p3);                                                       \
        *(uint2a*)((Pp) + st * 1152 + l16 * 72 + tt * 32 + quad * 8) = v_;          \
      }                                                                             \
    }                                                                               \
    _Pragma("unroll") for (int st = 0; st < 2; ++st) {                              \
      bf8a pf = *(const bf8a*)((Pp) + st * 1152 + l16 * 72 + quad * 16);            \
      __builtin_amdgcn_s_setprio(1);                                                \
      _Pragma("unroll") for (int nt = 0; nt < 4; ++nt)                              \
        oacc[st][nt] = MFMA_BF16(vf[nt], pf, oacc[st][nt]);                         \
      __builtin_amdgcn_s_setprio(0);                                                \
    }                                                                               \
  }

__global__ __launch_bounds__(256, 3) void attn_fused(
    const u16* __restrict__ Qw, const u16* __restrict__ Kw, const u16* __restrict__ Vw,
    const u16* __restrict__ EBp, u16* __restrict__ Ao) {
  // LDS: [0,18432) = union{ 2-stage per-wave P tiles [2][4][2304 B] (main) |
  //   Obuf float[4][16][66] (epilogue, 16896 B) }; [18432,18688) Lbuf float[4][16].
  __shared__ __align__(16) char smem[18688];
  const int tid = threadIdx.x, lane = tid & 63, w = tid >> 6;
  const int quad = lane >> 4, l16 = lane & 15;
  // supertile swizzle: 64 consecutive blocks = 16 qt x 4 pairs
  const int id = blockIdx.y * 64 + blockIdx.x;
  const int sst = id >> 6, wi = id & 63;
  const int qt = ((sst & 3) << 4) | (wi & 15);
  const int pair = ((sst >> 2) << 2) | (wi >> 4);
  const int bb = pair >> 4, hh = pair & 15;
  const u16* Qp = Qw + pair * (2048 * 64);
  const u16* Kp = Kw + pair * (2048 * 64);
  const u16* Vp = Vw + pair * (64 * 2048);
  const int s0 = qt * 32;  // block's 32 q-rows (shared by all waves)
  char* const PwA = smem + w * 2304;         // [2 st][16 s][36 t] u16 (pad 36)
  char* const PwB = smem + 9216 + w * 2304;  // stage-B copy

  bf8a qf[2][2];  // B-operand (Q^T): [st][ks]; n=s, k=d
#pragma unroll
  for (int st = 0; st < 2; ++st)
#pragma unroll
    for (int ks = 0; ks < 2; ++ks)
      qf[st][ks] = *(const bf8a*)(Qp + (s0 + st * 16 + l16) * 64 + ks * 32 + quad * 8);

  f32x4 oacc[2][4];  // O^T partial: [st][nt]; e = nt*16+quad*4+r, s = st*16+l16
#pragma unroll
  for (int i = 0; i < 2; ++i)
#pragma unroll
    for (int j = 0; j < 4; ++j) oacc[i][j] = f32x4{0.f, 0.f, 0.f, 0.f};
  float lsum[2] = {0.f, 0.f};  // per-lane partial row-sum of |p| (exp of logit)
  const float c1 = 0.125f * 1.44269504088896340736f;  // scale * log2(e)

  bf8a kfA[2][2], kfB[2][2];
  uint2 ebA[2][2], ebB[2][2];
  PREFETCH_KE(kfA, ebA, 0)
  __builtin_amdgcn_sched_barrier(0);
  for (int kt = 0; kt < 16; kt += 2) {
    PREFETCH_KE(kfB, ebB, kt + 1)
    __builtin_amdgcn_sched_barrier(0);  // pin B-prefetch issue before COMPUTE(A)
    COMPUTE(kfA, ebA, PwA, kt)
    __builtin_amdgcn_sched_barrier(0);
    PREFETCH_KE(kfA, ebA, (kt + 2) & 15)  // wraps to 0 on last iter (harmless, L2-hit)
    __builtin_amdgcn_sched_barrier(0);  // pin A-prefetch issue before COMPUTE(B)
    COMPUTE(kfB, ebB, PwB, kt + 1)
    __builtin_amdgcn_sched_barrier(0);
  }

  // ---------------- merge epilogue (plain sums, 2 st-passes) ----------------
  __syncthreads();  // all waves done reading P (Obuf aliases P regions)
  float* const Obuf = (float*)smem;             // [4][16 s][66 e]
  float* const Lbuf = (float*)(smem + 18432);   // [4][16 s]
#pragma unroll
  for (int st = 0; st < 2; ++st) {
    float ls = lsum[st];
    ls += __shfl_xor(ls, 16);
    ls += __shfl_xor(ls, 32);
    if (lane < 16) Lbuf[w * 16 + l16] = ls;
#pragma unroll
    for (int nt = 0; nt < 4; ++nt)
      *(float4a*)&Obuf[w * 1056 + l16 * 66 + nt * 16 + quad * 4] = (float4){
          oacc[st][nt][0], oacc[st][nt][1], oacc[st][nt][2], oacc[st][nt][3]};
    __syncthreads();
    // sum across waves + write: s = tid&15, e = (tid>>4)*4 + [0,4)
    {
      const int s_ = tid & 15, eg = (tid >> 4) * 4;
      float a0 = 0.f, a1 = 0.f, a2 = 0.f, a3 = 0.f;
#pragma unroll
      for (int wp = 0; wp < 4; ++wp) {
        const float4 x = *(const float4a*)&Obuf[wp * 1056 + s_ * 66 + eg];
        a0 += x.x; a1 += x.y; a2 += x.z; a3 += x.w;
      }
      const float lt = Lbuf[s_] + Lbuf[16 + s_] + Lbuf[32 + s_] + Lbuf[48 + s_];
      const float inv = 1.0f / lt;
      ushort4 o;
      o.x = f2b(a0 * inv); o.y = f2b(a1 * inv); o.z = f2b(a2 * inv); o.w = f2b(a3 * inv);
      *(ushort4a*)(Ao + ((s0 + st * 16 + s_) * 2 + bb) * 1024 + hh * 64 + eg) = o;
    }
    if (st == 0) __syncthreads();  // before pass 1 overwrites Obuf/Lbuf
  }
}

// ---------------------------------------------------------------------------
extern "C" void kernel_launch(void* const* d_in, const int* in_sizes, int n_in,
                              void* d_out, int out_size, void* d_ws, size_t ws_size,
                              hipStream_t stream) {
  const float* src = (const float*)d_in[0];
  const float* eb = (const float*)d_in[1];
  const float* wq = (const float*)d_in[2];
  const float* bq = (const float*)d_in[3];
  const float* wk = (const float*)d_in[4];
  const float* bk = (const float*)d_in[5];
  const float* wv = (const float*)d_in[6];
  const float* bv = (const float*)d_in[7];
  const float* wo = (const float*)d_in[8];
  const float* bo = (const float*)d_in[9];
  u16* ws = (u16*)d_ws;
  const size_t MM = 1024 * 1024;
  u16* wqT = ws;             // bf16 [N][K]
  u16* wkT = ws + MM;
  u16* wvT = ws + 2 * MM;
  u16* woT = ws + 3 * MM;
  u16* srcB = ws + 4 * MM;   // bf16 [4096][1024] -- dead after QKV GEMM
  u16* eb2 = ws + 4 * MM;    // bf16 tiled signed-exp EB (aliases srcB, written after)
  u16* qW = ws + 8 * MM;     // bf16 [32][2048][64]
  u16* kW = ws + 12 * MM;    // bf16 [32][2048][64]
  u16* vW = ws + 16 * MM;    // bf16 [32][64][2048] (V^T)
  u16* aO = ws + 20 * MM;    // bf16 [4096][1024]
  float* out = (float*)d_out;

  convert_src<<<dim3(4096), 256, 0, stream>>>(src, srcB);
  transpose4<<<dim3(16, 16, 4), 256, 0, stream>>>(wq, wk, wv, wo, wqT, wkT, wvT, woT);
  gemm_bt<<<dim3(8, 32, 3), 256, 0, stream>>>(srcB, wqT, wkT, wvT, bq, bk, bv,
                                              qW, kW, vW, nullptr, 0);
  prep_eb<<<dim3(4096), 256, 0, stream>>>(eb, eb2);  // after QKV GEMM (aliases srcB)
  attn_fused<<<dim3(64, 32), 256, 0, stream>>>(qW, kW, vW, eb2, aO);
  gemm_bt<<<dim3(8, 32, 1), 256, 0, stream>>>(aO, woT, woT, woT, bo, bo, bo,
                                              nullptr, nullptr, nullptr, out, 1);
}

// Round 3
// 285.758 us; speedup vs baseline: 1.1003x; 1.1003x over previous
//
#include <hip/hip_runtime.h>
#include <stdint.h>

typedef unsigned short u16;
typedef unsigned int u32;

typedef __bf16 bf8 __attribute__((ext_vector_type(8)));
typedef bf8 bf8a __attribute__((may_alias));
typedef float f32x4 __attribute__((ext_vector_type(4)));
typedef uint2 uint2a __attribute__((may_alias));
typedef ushort4 ushort4a __attribute__((may_alias));
typedef float4 float4a __attribute__((may_alias));

#define MFMA_BF16(a, b, c) __builtin_amdgcn_mfma_f32_16x16x32_bf16((a), (b), (c), 0, 0, 0)

__device__ __forceinline__ u16 f2b(float x) {
  u32 u = __float_as_uint(x);
  return (u16)((u + 0x7fffu + ((u >> 16) & 1u)) >> 16);  // RNE
}
__device__ __forceinline__ u32 pack2(float a, float b) {  // two f32 -> packed bf16x2 (sign-preserving)
  u32 ua = __float_as_uint(a), ub = __float_as_uint(b);
  return ((ua + 0x8000u) >> 16) | ((ub + 0x8000u) & 0xffff0000u);
}
__device__ __forceinline__ void async16(const u16* g, void* l) {
  __builtin_amdgcn_global_load_lds((const __attribute__((address_space(1))) u32*)g,
                                   (__attribute__((address_space(3))) u32*)l, 16, 0, 0);
}

// ---------------------------------------------------------------------------
// src convert: fp32 [4096][1024] -> bf16 same layout. 1 float4 per thread.
// ---------------------------------------------------------------------------
__global__ __launch_bounds__(256) void convert_src(const float* __restrict__ src,
                                                   u16* __restrict__ dst) {
  const int i = blockIdx.x * 256 + threadIdx.x;  // float4 index
  float4 v = *(const float4a*)(src + i * 4);
  ushort4 o;
  o.x = f2b(v.x); o.y = f2b(v.y); o.z = f2b(v.z); o.w = f2b(v.w);
  *(ushort4a*)(dst + i * 4) = o;
}

// ---------------------------------------------------------------------------
// EB precompute: fp32 [2048][2048] -> bf16 sign(b)*exp(b), 16x16-tiled layout:
// E2[(s>>4)*128 + (t>>4)][ (s&15)*16 + (t&15) ]  (256 elem = 512 B per tile)
// ---------------------------------------------------------------------------
__global__ __launch_bounds__(256) void prep_eb(const float* __restrict__ EB,
                                               u16* __restrict__ E2) {
  const int gid = blockIdx.x * 256 + threadIdx.x;
  const int s = gid >> 9;            // 512 float4 per row
  const int t = (gid & 511) * 4;
  const float4 v = *(const float4a*)(EB + s * 2048 + t);
  const float c2 = 1.44269504088896340736f;  // log2(e)
  ushort4 o;
  o.x = f2b(__builtin_amdgcn_exp2f(v.x * c2)) | (u16)((__float_as_uint(v.x) >> 16) & 0x8000u);
  o.y = f2b(__builtin_amdgcn_exp2f(v.y * c2)) | (u16)((__float_as_uint(v.y) >> 16) & 0x8000u);
  o.z = f2b(__builtin_amdgcn_exp2f(v.z * c2)) | (u16)((__float_as_uint(v.z) >> 16) & 0x8000u);
  o.w = f2b(__builtin_amdgcn_exp2f(v.w * c2)) | (u16)((__float_as_uint(v.w) >> 16) & 0x8000u);
  const int ti = ((s >> 4) * 128 + (t >> 4)) * 256 + (s & 15) * 16 + (t & 15);
  *(ushort4a*)(E2 + ti) = o;
}

// ---------------------------------------------------------------------------
// Weight transpose+convert: w fp32 [K=1024][N=1024] -> wT bf16 [N][K]
// ---------------------------------------------------------------------------
__global__ __launch_bounds__(256) void transpose4(
    const float* __restrict__ w0, const float* __restrict__ w1,
    const float* __restrict__ w2, const float* __restrict__ w3,
    u16* __restrict__ t0, u16* __restrict__ t1, u16* __restrict__ t2, u16* __restrict__ t3) {
  const int z = blockIdx.z;
  const float* W = z == 0 ? w0 : z == 1 ? w1 : z == 2 ? w2 : w3;
  u16* T = z == 0 ? t0 : z == 1 ? t1 : z == 2 ? t2 : t3;
  __shared__ __align__(8) u16 tile[64][68];
  const int tid = threadIdx.x;
  const int ty = tid >> 4, tx = tid & 15;
  const int kb = blockIdx.y * 64, nb = blockIdx.x * 64;
#pragma unroll
  for (int i = 0; i < 4; ++i) {
    int lk = ty + i * 16;
    float4 v = *(const float4a*)(W + (kb + lk) * 1024 + nb + tx * 4);
    ushort4 h;
    h.x = f2b(v.x); h.y = f2b(v.y); h.z = f2b(v.z); h.w = f2b(v.w);
    *(ushort4a*)&tile[lk][tx * 4] = h;
  }
  __syncthreads();
#pragma unroll
  for (int i = 0; i < 4; ++i) {
    int ln = ty + i * 16;
    ushort4 v;
    v.x = tile[tx * 4 + 0][ln];
    v.y = tile[tx * 4 + 1][ln];
    v.z = tile[tx * 4 + 2][ln];
    v.w = tile[tx * 4 + 3][ln];
    *(ushort4a*)(T + (nb + ln) * 1024 + kb + tx * 4) = v;
  }
}

// ---------------------------------------------------------------------------
// GEMM: C[M][N] = A[M,1024] * Bt[N,1024]^T + bias[n]   (m97 structure)
// ---------------------------------------------------------------------------
__global__ __launch_bounds__(256) void gemm_bt(
    const u16* __restrict__ A,
    const u16* __restrict__ B0, const u16* __restrict__ B1, const u16* __restrict__ B2,
    const float* __restrict__ c0, const float* __restrict__ c1, const float* __restrict__ c2,
    u16* __restrict__ O0, u16* __restrict__ O1, u16* __restrict__ O2,
    float* __restrict__ Of, int plain) {
  __shared__ __align__(16) u16 sm[8192];
  u16* As = sm;
  u16* Bs = sm + 4096;
  const int tid = threadIdx.x, lane = tid & 63, w = tid >> 6;
  const int wm = w >> 1, wn = w & 1, quad = lane >> 4, l16 = lane & 15;
  const int z = blockIdx.z;
  const u16* Bt = z == 0 ? B0 : (z == 1 ? B1 : B2);
  const float* bi = z == 0 ? c0 : (z == 1 ? c1 : c2);
  u16* O = z == 0 ? O0 : (z == 1 ? O1 : O2);
  const int row0 = blockIdx.y * 128, col0 = blockIdx.x * 128;

  f32x4 acc[4][4];
#pragma unroll
  for (int i = 0; i < 4; ++i)
#pragma unroll
    for (int j = 0; j < 4; ++j) acc[i][j] = f32x4{0.f, 0.f, 0.f, 0.f};

  const int e0 = tid, e1 = tid + 256;
  const int r0 = e0 >> 2, cc0 = (e0 & 3) * 8;
  const int r1 = e1 >> 2, cc1 = (e1 & 3) * 8;
  const u32 lb0 = (u32)(w * 64) * 16;
  const u32 lb1 = (u32)(w * 64 + 256) * 16;

  for (int k0 = 0; k0 < 1024; k0 += 32) {
    __syncthreads();
    async16(A + (row0 + r0) * 1024 + k0 + cc0, (char*)As + lb0);
    async16(A + (row0 + r1) * 1024 + k0 + cc1, (char*)As + lb1);
    async16(Bt + (col0 + r0) * 1024 + k0 + cc0, (char*)Bs + lb0);
    async16(Bt + (col0 + r1) * 1024 + k0 + cc1, (char*)Bs + lb1);
    __syncthreads();
    bf8a af[4], bfr[4];
#pragma unroll
    for (int i = 0; i < 4; ++i) {
      af[i] = *(const bf8a*)(As + (wm * 64 + i * 16 + l16) * 32 + quad * 8);
      bfr[i] = *(const bf8a*)(Bs + (wn * 64 + i * 16 + l16) * 32 + quad * 8);
    }
#pragma unroll
    for (int mt = 0; mt < 4; ++mt)
#pragma unroll
      for (int nt = 0; nt < 4; ++nt) acc[mt][nt] = MFMA_BF16(af[mt], bfr[nt], acc[mt][nt]);
  }

#pragma unroll
  for (int nt = 0; nt < 4; ++nt) {
    const int col = col0 + wn * 64 + nt * 16 + l16;
    const float bcol = bi[col];
#pragma unroll
    for (int mt = 0; mt < 4; ++mt) {
#pragma unroll
      for (int r = 0; r < 4; ++r) {
        const int rm = row0 + wm * 64 + mt * 16 + quad * 4 + r;
        const float fv = acc[mt][nt][r] + bcol;
        if (plain) {
          Of[rm * 1024 + col] = fv;
        } else {
          const u16 hv = f2b(fv);
          const int s = rm >> 1, b_ = rm & 1, hh = col >> 6, e = col & 63;
          const int p = b_ * 16 + hh;
          if (z < 2) O[(p * 2048 + s) * 64 + e] = hv;  // [pair][s][64]
          else O[(p * 64 + e) * 2048 + s] = hv;        // [pair][e][s] (V^T)
        }
      }
    }
  }
}

// ---------------------------------------------------------------------------
// Flash attention v11: latency attack after v9/v10 showed the register
// pipeline never materializes (VGPR 68/76) and every load JIT-misses L2.
//  (a) XCD-pinned mapping: xcd=id&7 (round-robin dispatch, m09); each XCD
//      exclusively owns 4 pairs -> K+V (2MB) stay L2-resident; pair-fast
//      ordering makes 4 same-qt blocks concurrent -> EB tile 1 miss + 3 hits.
//  (b) K tile via global_load_lds single-buffer 2-barrier staging (the
//      proven m97/gemm_bt structure): DMA for stage kt issued before the
//      2nd barrier, drain covered by other resident blocks. XOR swizzle
//      byte^=(row&7)<<4, applied as pre-swizzled GLOBAL source + swizzled
//      LDS read (linear DMA dest, rule #21).
//  (c) V/EB JIT register loads issued inside the stage window (the barrier's
//      vmcnt(0) drain keeps them in flight with the DMA); L2-hits after (a).
//  (d) sched_barriers removed (proven null); setprio kept; single P buffer.
// ---------------------------------------------------------------------------
__global__ __launch_bounds__(256, 3) void attn_fused(
    const u16* __restrict__ Qw, const u16* __restrict__ Kw, const u16* __restrict__ Vw,
    const u16* __restrict__ EBp, u16* __restrict__ Ao) {
  // LDS map: [0,16384) Ks = K tile [128 t][64 d] bf16, XOR-swizzled rows;
  //          [16384,25600) per-wave P tiles [4][2304 B];
  //          [25600,25856) Lbuf float[4][16].
  // Epilogue: Obuf float[4][16][66] (16896 B) aliases [0,16896) after sync.
  __shared__ __align__(16) char smem[25856];
  u16* const Ks = (u16*)smem;
  const int tid = threadIdx.x, lane = tid & 63, w = tid >> 6;
  const int quad = lane >> 4, l16 = lane & 15;
  const int id = blockIdx.x;
  const int xcd = id & 7, idx = id >> 3;
  const int pair = xcd * 4 + (idx & 3);  // pair fast: 4 pairs pinned per XCD
  const int qt = idx >> 2;               // qt slow: EB window advances slowly
  const int bb = pair >> 4, hh = pair & 15;
  const u16* Qp = Qw + pair * (2048 * 64);
  const u16* Kp = Kw + pair * (2048 * 64);
  const u16* Vp = Vw + pair * (64 * 2048);
  const int s0 = qt * 32;  // block's 32 q-rows (shared by all waves)
  char* const Pw = smem + 16384 + w * 2304;  // [2 st][16 s][36 t] u16 (pad 36)

  bf8a qf[2][2];  // B-operand (Q^T): [st][ks]; n=s, k=d
#pragma unroll
  for (int st = 0; st < 2; ++st)
#pragma unroll
    for (int ks = 0; ks < 2; ++ks)
      qf[st][ks] = *(const bf8a*)(Qp + (s0 + st * 16 + l16) * 64 + ks * 32 + quad * 8);

  f32x4 oacc[2][4];  // O^T partial: [st][nt]; e = nt*16+quad*4+r, s = st*16+l16
#pragma unroll
  for (int i = 0; i < 2; ++i)
#pragma unroll
    for (int j = 0; j < 4; ++j) oacc[i][j] = f32x4{0.f, 0.f, 0.f, 0.f};
  float lsum[2] = {0.f, 0.f};  // per-lane partial row-sum of |p|
  const float c1 = 0.125f * 1.44269504088896340736f;  // scale * log2(e)

  // DMA source pre-swizzle: lane writes LDS byte L=(c*4+w)*1024+lane*16
  // = row*128 + chunk*16 with row=(c*4+w)*8+(lane>>3), chunk=lane&7.
  // Stored-at-L content must be element at chunk^(row&7) = (lane&7)^(lane>>3).
  const int r8 = lane >> 3;
  const int c16s = (lane & 7) ^ r8;

  for (int kt = 0; kt < 16; ++kt) {
    __syncthreads();  // prev iteration done reading Ks
    // --- K tile [128][64] stage kt -> LDS (swizzled source, linear dest) ---
#pragma unroll
    for (int c = 0; c < 4; ++c) {
      const int row = c * 32 + w * 8 + r8;
      async16(Kp + (kt * 128 + row) * 64 + c16s * 8, (char*)Ks + (c * 4 + w) * 1024);
    }
    const int tbase = kt * 128 + w * 32;  // wave's 32-t strip
    // --- V / EB register loads, in flight alongside the DMA ---
    bf8a vf[4];  // V^T A-operand rows e: [nt], k = t strip
#pragma unroll
    for (int nt = 0; nt < 4; ++nt)
      vf[nt] = *(const bf8a*)(Vp + (nt * 16 + l16) * 2048 + tbase + quad * 8);
    uint2 eb[2][2];  // signed-exp EB bf16 tiles
    {
      const int tb16 = kt * 8 + w * 2;
#pragma unroll
      for (int st = 0; st < 2; ++st)
#pragma unroll
        for (int tt = 0; tt < 2; ++tt)
          eb[st][tt] = *(const uint2a*)(EBp + ((qt * 2 + st) * 128 + tb16 + tt) * 256 +
                                        l16 * 16 + quad * 4);
    }
    __syncthreads();  // vmcnt(0) drain: K staged, V/EB landed

    // --- K fragments from LDS (swizzled read) ---
    bf8a kf[2][2];
#pragma unroll
    for (int tt = 0; tt < 2; ++tt) {
      const int row = w * 32 + tt * 16 + l16;  // row&7 == l16&7
#pragma unroll
      for (int ks = 0; ks < 2; ++ks) {
        const int cc = ((ks * 4 + quad) ^ (l16 & 7)) * 8;  // u16 offset in row
        kf[tt][ks] = *(const bf8a*)(Ks + row * 64 + cc);
      }
    }
    // --- S^T = K * Q^T : D[row=t][col=s] ---
    f32x4 sacc[2][2];  // [tt][st]
    __builtin_amdgcn_s_setprio(1);
#pragma unroll
    for (int tt = 0; tt < 2; ++tt)
#pragma unroll
      for (int st = 0; st < 2; ++st) {
        f32x4 t0 = f32x4{0.f, 0.f, 0.f, 0.f};
        t0 = MFMA_BF16(kf[tt][0], qf[st][0], t0);
        sacc[tt][st] = MFMA_BF16(kf[tt][1], qf[st][1], t0);
      }
    __builtin_amdgcn_s_setprio(0);
    // --- p = exp2(qk*c1) * signed_exp_bias, pack, P -> LDS, |p| accum ---
#pragma unroll
    for (int st = 0; st < 2; ++st) {
#pragma unroll
      for (int tt = 0; tt < 2; ++tt) {
        const uint2 e_ = eb[st][tt];
        const float g0 = __uint_as_float(e_.x << 16);
        const float g1 = __uint_as_float(e_.x & 0xffff0000u);
        const float g2 = __uint_as_float(e_.y << 16);
        const float g3 = __uint_as_float(e_.y & 0xffff0000u);
        const float p0 = __builtin_amdgcn_exp2f(sacc[tt][st][0] * c1) * g0;
        const float p1 = __builtin_amdgcn_exp2f(sacc[tt][st][1] * c1) * g1;
        const float p2 = __builtin_amdgcn_exp2f(sacc[tt][st][2] * c1) * g2;
        const float p3 = __builtin_amdgcn_exp2f(sacc[tt][st][3] * c1) * g3;
        lsum[st] += (__builtin_fabsf(p0) + __builtin_fabsf(p1)) +
                    (__builtin_fabsf(p2) + __builtin_fabsf(p3));
        uint2 v_;
        v_.x = pack2(p0, p1);
        v_.y = pack2(p2, p3);
        *(uint2a*)(Pw + st * 1152 + l16 * 72 + tt * 32 + quad * 8) = v_;
      }
    }
    // --- PV: O^T += V^T * P ; A = vf (m=e), B = pf (n=s, k=t) ---
#pragma unroll
    for (int st = 0; st < 2; ++st) {
      bf8a pf = *(const bf8a*)(Pw + st * 1152 + l16 * 72 + quad * 16);
      __builtin_amdgcn_s_setprio(1);
#pragma unroll
      for (int nt = 0; nt < 4; ++nt) oacc[st][nt] = MFMA_BF16(vf[nt], pf, oacc[st][nt]);
      __builtin_amdgcn_s_setprio(0);
    }
  }

  // ---------------- merge epilogue (plain sums, 2 st-passes) ----------------
  __syncthreads();  // all waves done with Ks/P (Obuf aliases them)
  float* const Obuf = (float*)smem;             // [4][16 s][66 e]
  float* const Lbuf = (float*)(smem + 25600);   // [4][16 s]
#pragma unroll
  for (int st = 0; st < 2; ++st) {
    float ls = lsum[st];
    ls += __shfl_xor(ls, 16);
    ls += __shfl_xor(ls, 32);
    if (lane < 16) Lbuf[w * 16 + l16] = ls;
#pragma unroll
    for (int nt = 0; nt < 4; ++nt)
      *(float4a*)&Obuf[w * 1056 + l16 * 66 + nt * 16 + quad * 4] = (float4){
          oacc[st][nt][0], oacc[st][nt][1], oacc[st][nt][2], oacc[st][nt][3]};
    __syncthreads();
    // sum across waves + write: s = tid&15, e = (tid>>4)*4 + [0,4)
    {
      const int s_ = tid & 15, eg = (tid >> 4) * 4;
      float a0 = 0.f, a1 = 0.f, a2 = 0.f, a3 = 0.f;
#pragma unroll
      for (int wp = 0; wp < 4; ++wp) {
        const float4 x = *(const float4a*)&Obuf[wp * 1056 + s_ * 66 + eg];
        a0 += x.x; a1 += x.y; a2 += x.z; a3 += x.w;
      }
      const float lt = Lbuf[s_] + Lbuf[16 + s_] + Lbuf[32 + s_] + Lbuf[48 + s_];
      const float inv = 1.0f / lt;
      ushort4 o;
      o.x = f2b(a0 * inv); o.y = f2b(a1 * inv); o.z = f2b(a2 * inv); o.w = f2b(a3 * inv);
      *(ushort4a*)(Ao + ((s0 + st * 16 + s_) * 2 + bb) * 1024 + hh * 64 + eg) = o;
    }
    if (st == 0) __syncthreads();  // before pass 1 overwrites Obuf/Lbuf
  }
}

// ---------------------------------------------------------------------------
extern "C" void kernel_launch(void* const* d_in, const int* in_sizes, int n_in,
                              void* d_out, int out_size, void* d_ws, size_t ws_size,
                              hipStream_t stream) {
  const float* src = (const float*)d_in[0];
  const float* eb = (const float*)d_in[1];
  const float* wq = (const float*)d_in[2];
  const float* bq = (const float*)d_in[3];
  const float* wk = (const float*)d_in[4];
  const float* bk = (const float*)d_in[5];
  const float* wv = (const float*)d_in[6];
  const float* bv = (const float*)d_in[7];
  const float* wo = (const float*)d_in[8];
  const float* bo = (const float*)d_in[9];
  u16* ws = (u16*)d_ws;
  const size_t MM = 1024 * 1024;
  u16* wqT = ws;             // bf16 [N][K]
  u16* wkT = ws + MM;
  u16* wvT = ws + 2 * MM;
  u16* woT = ws + 3 * MM;
  u16* srcB = ws + 4 * MM;   // bf16 [4096][1024] -- dead after QKV GEMM
  u16* eb2 = ws + 4 * MM;    // bf16 tiled signed-exp EB (aliases srcB, written after)
  u16* qW = ws + 8 * MM;     // bf16 [32][2048][64]
  u16* kW = ws + 12 * MM;    // bf16 [32][2048][64]
  u16* vW = ws + 16 * MM;    // bf16 [32][64][2048] (V^T)
  u16* aO = ws + 20 * MM;    // bf16 [4096][1024]
  float* out = (float*)d_out;

  convert_src<<<dim3(4096), 256, 0, stream>>>(src, srcB);
  transpose4<<<dim3(16, 16, 4), 256, 0, stream>>>(wq, wk, wv, wo, wqT, wkT, wvT, woT);
  gemm_bt<<<dim3(8, 32, 3), 256, 0, stream>>>(srcB, wqT, wkT, wvT, bq, bk, bv,
                                              qW, kW, vW, nullptr, 0);
  prep_eb<<<dim3(4096), 256, 0, stream>>>(eb, eb2);  // after QKV GEMM (aliases srcB)
  attn_fused<<<dim3(2048), 256, 0, stream>>>(qW, kW, vW, eb2, aO);
  gemm_bt<<<dim3(8, 32, 1), 256, 0, stream>>>(aO, woT, woT, woT, bo, bo, bo,
                                              nullptr, nullptr, nullptr, out, 1);
}

// Round 4
// 283.537 us; speedup vs baseline: 1.1089x; 1.0078x over previous
//
#include <hip/hip_runtime.h>
#include <stdint.h>

typedef unsigned short u16;
typedef unsigned int u32;

typedef __bf16 bf8 __attribute__((ext_vector_type(8)));
typedef bf8 bf8a __attribute__((may_alias));
typedef float f32x4 __attribute__((ext_vector_type(4)));
typedef uint2 uint2a __attribute__((may_alias));
typedef ushort4 ushort4a __attribute__((may_alias));
typedef float4 float4a __attribute__((may_alias));

#define MFMA_BF16(a, b, c) __builtin_amdgcn_mfma_f32_16x16x32_bf16((a), (b), (c), 0, 0, 0)

__device__ __forceinline__ u16 f2b(float x) {
  u32 u = __float_as_uint(x);
  return (u16)((u + 0x7fffu + ((u >> 16) & 1u)) >> 16);  // RNE
}
__device__ __forceinline__ u32 pack2(float a, float b) {  // two f32 -> packed bf16x2 (sign-preserving)
  u32 ua = __float_as_uint(a), ub = __float_as_uint(b);
  return ((ua + 0x8000u) >> 16) | ((ub + 0x8000u) & 0xffff0000u);
}
__device__ __forceinline__ void async16(const u16* g, void* l) {
  __builtin_amdgcn_global_load_lds((const __attribute__((address_space(1))) u32*)g,
                                   (__attribute__((address_space(3))) u32*)l, 16, 0, 0);
}

// ---------------------------------------------------------------------------
// src convert: fp32 [4096][1024] -> bf16 same layout. 1 float4 per thread.
// ---------------------------------------------------------------------------
__global__ __launch_bounds__(256) void convert_src(const float* __restrict__ src,
                                                   u16* __restrict__ dst) {
  const int i = blockIdx.x * 256 + threadIdx.x;  // float4 index
  float4 v = *(const float4a*)(src + i * 4);
  ushort4 o;
  o.x = f2b(v.x); o.y = f2b(v.y); o.z = f2b(v.z); o.w = f2b(v.w);
  *(ushort4a*)(dst + i * 4) = o;
}

// ---------------------------------------------------------------------------
// EB precompute: fp32 [2048][2048] -> bf16 sign(b)*exp(b), 16x16-tiled layout:
// E2[(s>>4)*128 + (t>>4)][ (s&15)*16 + (t&15) ]  (256 elem = 512 B per tile)
// ---------------------------------------------------------------------------
__global__ __launch_bounds__(256) void prep_eb(const float* __restrict__ EB,
                                               u16* __restrict__ E2) {
  const int gid = blockIdx.x * 256 + threadIdx.x;
  const int s = gid >> 9;            // 512 float4 per row
  const int t = (gid & 511) * 4;
  const float4 v = *(const float4a*)(EB + s * 2048 + t);
  const float c2 = 1.44269504088896340736f;  // log2(e)
  ushort4 o;
  o.x = f2b(__builtin_amdgcn_exp2f(v.x * c2)) | (u16)((__float_as_uint(v.x) >> 16) & 0x8000u);
  o.y = f2b(__builtin_amdgcn_exp2f(v.y * c2)) | (u16)((__float_as_uint(v.y) >> 16) & 0x8000u);
  o.z = f2b(__builtin_amdgcn_exp2f(v.z * c2)) | (u16)((__float_as_uint(v.z) >> 16) & 0x8000u);
  o.w = f2b(__builtin_amdgcn_exp2f(v.w * c2)) | (u16)((__float_as_uint(v.w) >> 16) & 0x8000u);
  const int ti = ((s >> 4) * 128 + (t >> 4)) * 256 + (s & 15) * 16 + (t & 15);
  *(ushort4a*)(E2 + ti) = o;
}

// ---------------------------------------------------------------------------
// Weight transpose+convert: w fp32 [K=1024][N=1024] -> wT bf16 [N][K]
// ---------------------------------------------------------------------------
__global__ __launch_bounds__(256) void transpose4(
    const float* __restrict__ w0, const float* __restrict__ w1,
    const float* __restrict__ w2, const float* __restrict__ w3,
    u16* __restrict__ t0, u16* __restrict__ t1, u16* __restrict__ t2, u16* __restrict__ t3) {
  const int z = blockIdx.z;
  const float* W = z == 0 ? w0 : z == 1 ? w1 : z == 2 ? w2 : w3;
  u16* T = z == 0 ? t0 : z == 1 ? t1 : z == 2 ? t2 : t3;
  __shared__ __align__(8) u16 tile[64][68];
  const int tid = threadIdx.x;
  const int ty = tid >> 4, tx = tid & 15;
  const int kb = blockIdx.y * 64, nb = blockIdx.x * 64;
#pragma unroll
  for (int i = 0; i < 4; ++i) {
    int lk = ty + i * 16;
    float4 v = *(const float4a*)(W + (kb + lk) * 1024 + nb + tx * 4);
    ushort4 h;
    h.x = f2b(v.x); h.y = f2b(v.y); h.z = f2b(v.z); h.w = f2b(v.w);
    *(ushort4a*)&tile[lk][tx * 4] = h;
  }
  __syncthreads();
#pragma unroll
  for (int i = 0; i < 4; ++i) {
    int ln = ty + i * 16;
    ushort4 v;
    v.x = tile[tx * 4 + 0][ln];
    v.y = tile[tx * 4 + 1][ln];
    v.z = tile[tx * 4 + 2][ln];
    v.w = tile[tx * 4 + 3][ln];
    *(ushort4a*)(T + (nb + ln) * 1024 + kb + tx * 4) = v;
  }
}

// ---------------------------------------------------------------------------
// GEMM: C[M][N] = A[M,1024] * Bt[N,1024]^T + bias[n]   (m97 structure)
// ---------------------------------------------------------------------------
__global__ __launch_bounds__(256) void gemm_bt(
    const u16* __restrict__ A,
    const u16* __restrict__ B0, const u16* __restrict__ B1, const u16* __restrict__ B2,
    const float* __restrict__ c0, const float* __restrict__ c1, const float* __restrict__ c2,
    u16* __restrict__ O0, u16* __restrict__ O1, u16* __restrict__ O2,
    float* __restrict__ Of, int plain) {
  __shared__ __align__(16) u16 sm[8192];
  u16* As = sm;
  u16* Bs = sm + 4096;
  const int tid = threadIdx.x, lane = tid & 63, w = tid >> 6;
  const int wm = w >> 1, wn = w & 1, quad = lane >> 4, l16 = lane & 15;
  const int z = blockIdx.z;
  const u16* Bt = z == 0 ? B0 : (z == 1 ? B1 : B2);
  const float* bi = z == 0 ? c0 : (z == 1 ? c1 : c2);
  u16* O = z == 0 ? O0 : (z == 1 ? O1 : O2);
  const int row0 = blockIdx.y * 128, col0 = blockIdx.x * 128;

  f32x4 acc[4][4];
#pragma unroll
  for (int i = 0; i < 4; ++i)
#pragma unroll
    for (int j = 0; j < 4; ++j) acc[i][j] = f32x4{0.f, 0.f, 0.f, 0.f};

  const int e0 = tid, e1 = tid + 256;
  const int r0 = e0 >> 2, cc0 = (e0 & 3) * 8;
  const int r1 = e1 >> 2, cc1 = (e1 & 3) * 8;
  const u32 lb0 = (u32)(w * 64) * 16;
  const u32 lb1 = (u32)(w * 64 + 256) * 16;

  for (int k0 = 0; k0 < 1024; k0 += 32) {
    __syncthreads();
    async16(A + (row0 + r0) * 1024 + k0 + cc0, (char*)As + lb0);
    async16(A + (row0 + r1) * 1024 + k0 + cc1, (char*)As + lb1);
    async16(Bt + (col0 + r0) * 1024 + k0 + cc0, (char*)Bs + lb0);
    async16(Bt + (col0 + r1) * 1024 + k0 + cc1, (char*)Bs + lb1);
    __syncthreads();
    bf8a af[4], bfr[4];
#pragma unroll
    for (int i = 0; i < 4; ++i) {
      af[i] = *(const bf8a*)(As + (wm * 64 + i * 16 + l16) * 32 + quad * 8);
      bfr[i] = *(const bf8a*)(Bs + (wn * 64 + i * 16 + l16) * 32 + quad * 8);
    }
#pragma unroll
    for (int mt = 0; mt < 4; ++mt)
#pragma unroll
      for (int nt = 0; nt < 4; ++nt) acc[mt][nt] = MFMA_BF16(af[mt], bfr[nt], acc[mt][nt]);
  }

#pragma unroll
  for (int nt = 0; nt < 4; ++nt) {
    const int col = col0 + wn * 64 + nt * 16 + l16;
    const float bcol = bi[col];
#pragma unroll
    for (int mt = 0; mt < 4; ++mt) {
#pragma unroll
      for (int r = 0; r < 4; ++r) {
        const int rm = row0 + wm * 64 + mt * 16 + quad * 4 + r;
        const float fv = acc[mt][nt][r] + bcol;
        if (plain) {
          Of[rm * 1024 + col] = fv;
        } else {
          const u16 hv = f2b(fv);
          const int s = rm >> 1, b_ = rm & 1, hh = col >> 6, e = col & 63;
          const int p = b_ * 16 + hh;
          if (z < 2) O[(p * 2048 + s) * 64 + e] = hv;  // [pair][s][64]
          else O[(p * 64 + e) * 2048 + s] = hv;        // [pair][e][s] (V^T)
        }
      }
    }
  }
}

// ---------------------------------------------------------------------------
// Flash attention v12 = v11 + T3 minimal 2-phase pipeline:
//  stage K(kt+1) DMA into the idle LDS buffer + V/EB(kt+1) register loads,
//  THEN compute kt from the other buffer, THEN one __syncthreads (vmcnt(0)
//  drain covered by the ~600cy compute phase). v11's stage->drain->compute
//  exposed a full load round-trip every iteration (2340 cy/block-iter slot
//  vs ~650 cy issue). The barrier-fence is the mechanism that makes the
//  register prefetch stick (v11 proved loads issued before __syncthreads
//  and consumed after are NOT sunk; v9/v10's barrier-free loop collapsed).
//  Named A/B register sets + Ks0/Ks1 (rule #20: no runtime-indexed arrays).
//  XCD pinning, swizzled K staging, signed-exp EB, setprio: kept from v11.
// ---------------------------------------------------------------------------
#define STAGE_K(Ksbuf, kt_)                                                         \
  {                                                                                 \
    _Pragma("unroll") for (int c = 0; c < 4; ++c) {                                 \
      const int row_ = c * 32 + w * 8 + r8;                                         \
      async16(Kp + ((kt_) * 128 + row_) * 64 + c16s * 8,                            \
              (char*)(Ksbuf) + (c * 4 + w) * 1024);                                 \
    }                                                                               \
  }

#define LOAD_VE(vf, eb, kt_)                                                        \
  {                                                                                 \
    const int tb_ = (kt_) * 128 + w * 32;                                           \
    _Pragma("unroll") for (int nt = 0; nt < 4; ++nt)                                \
      vf[nt] = *(const bf8a*)(Vp + (nt * 16 + l16) * 2048 + tb_ + quad * 8);        \
    const int tb16_ = (kt_) * 8 + w * 2;                                            \
    _Pragma("unroll") for (int st = 0; st < 2; ++st)                                \
      _Pragma("unroll") for (int tt = 0; tt < 2; ++tt)                              \
        eb[st][tt] = *(const uint2a*)(EBp + ((qt * 2 + st) * 128 + tb16_ + tt) * 256 \
                                      + l16 * 16 + quad * 4);                       \
  }

#define COMPUTE(Ksbuf, vf, eb)                                                      \
  {                                                                                 \
    bf8a kf[2][2];                                                                  \
    _Pragma("unroll") for (int tt = 0; tt < 2; ++tt) {                              \
      const int row_ = w * 32 + tt * 16 + l16; /* row_&7 == l16&7 */                \
      _Pragma("unroll") for (int ks = 0; ks < 2; ++ks) {                            \
        const int cc_ = ((ks * 4 + quad) ^ (l16 & 7)) * 8;                          \
        kf[tt][ks] = *(const bf8a*)((Ksbuf) + row_ * 64 + cc_);                     \
      }                                                                             \
    }                                                                               \
    f32x4 sacc[2][2];                                                               \
    __builtin_amdgcn_s_setprio(1);                                                  \
    _Pragma("unroll") for (int tt = 0; tt < 2; ++tt)                                \
      _Pragma("unroll") for (int st = 0; st < 2; ++st) {                            \
        f32x4 t0_ = f32x4{0.f, 0.f, 0.f, 0.f};                                      \
        t0_ = MFMA_BF16(kf[tt][0], qf[st][0], t0_);                                 \
        sacc[tt][st] = MFMA_BF16(kf[tt][1], qf[st][1], t0_);                        \
      }                                                                             \
    __builtin_amdgcn_s_setprio(0);                                                  \
    _Pragma("unroll") for (int st = 0; st < 2; ++st) {                              \
      _Pragma("unroll") for (int tt = 0; tt < 2; ++tt) {                            \
        const uint2 e_ = eb[st][tt];                                                \
        const float g0 = __uint_as_float(e_.x << 16);                               \
        const float g1 = __uint_as_float(e_.x & 0xffff0000u);                       \
        const float g2 = __uint_as_float(e_.y << 16);                               \
        const float g3 = __uint_as_float(e_.y & 0xffff0000u);                       \
        const float p0 = __builtin_amdgcn_exp2f(sacc[tt][st][0] * c1) * g0;         \
        const float p1 = __builtin_amdgcn_exp2f(sacc[tt][st][1] * c1) * g1;         \
        const float p2 = __builtin_amdgcn_exp2f(sacc[tt][st][2] * c1) * g2;         \
        const float p3 = __builtin_amdgcn_exp2f(sacc[tt][st][3] * c1) * g3;         \
        lsum[st] += (__builtin_fabsf(p0) + __builtin_fabsf(p1)) +                   \
                    (__builtin_fabsf(p2) + __builtin_fabsf(p3));                    \
        uint2 v_;                                                                   \
        v_.x = pack2(p0, p1);                                                       \
        v_.y = pack2(p2, p3);                                                       \
        *(uint2a*)(Pw + st * 1152 + l16 * 72 + tt * 32 + quad * 8) = v_;            \
      }                                                                             \
    }                                                                               \
    _Pragma("unroll") for (int st = 0; st < 2; ++st) {                              \
      bf8a pf = *(const bf8a*)(Pw + st * 1152 + l16 * 72 + quad * 16);              \
      __builtin_amdgcn_s_setprio(1);                                                \
      _Pragma("unroll") for (int nt = 0; nt < 4; ++nt)                              \
        oacc[st][nt] = MFMA_BF16(vf[nt], pf, oacc[st][nt]);                         \
      __builtin_amdgcn_s_setprio(0);                                                \
    }                                                                               \
  }

__global__ __launch_bounds__(256, 3) void attn_fused(
    const u16* __restrict__ Qw, const u16* __restrict__ Kw, const u16* __restrict__ Vw,
    const u16* __restrict__ EBp, u16* __restrict__ Ao) {
  // LDS map: [0,16384) Ks0, [16384,32768) Ks1  (K tile [128 t][64 d] bf16,
  //            XOR-swizzled rows, double-buffered);
  //          [32768,41984) per-wave P tiles [4][2304 B];
  //          [41984,42240) Lbuf float[4][16].
  // Epilogue: Obuf float[4][16][66] (16896 B) aliases [0,16896) after sync.
  __shared__ __align__(16) char smem[42240];
  u16* const Ks0 = (u16*)smem;
  u16* const Ks1 = (u16*)(smem + 16384);
  const int tid = threadIdx.x, lane = tid & 63, w = tid >> 6;
  const int quad = lane >> 4, l16 = lane & 15;
  const int id = blockIdx.x;
  const int xcd = id & 7, idx = id >> 3;
  const int pair = xcd * 4 + (idx & 3);  // pair fast: 4 pairs pinned per XCD
  const int qt = idx >> 2;               // qt slow: EB window advances slowly
  const int bb = pair >> 4, hh = pair & 15;
  const u16* Qp = Qw + pair * (2048 * 64);
  const u16* Kp = Kw + pair * (2048 * 64);
  const u16* Vp = Vw + pair * (64 * 2048);
  const int s0 = qt * 32;  // block's 32 q-rows (shared by all waves)
  char* const Pw = smem + 32768 + w * 2304;  // [2 st][16 s][36 t] u16 (pad 36)

  bf8a qf[2][2];  // B-operand (Q^T): [st][ks]; n=s, k=d
#pragma unroll
  for (int st = 0; st < 2; ++st)
#pragma unroll
    for (int ks = 0; ks < 2; ++ks)
      qf[st][ks] = *(const bf8a*)(Qp + (s0 + st * 16 + l16) * 64 + ks * 32 + quad * 8);

  f32x4 oacc[2][4];  // O^T partial: [st][nt]; e = nt*16+quad*4+r, s = st*16+l16
#pragma unroll
  for (int i = 0; i < 2; ++i)
#pragma unroll
    for (int j = 0; j < 4; ++j) oacc[i][j] = f32x4{0.f, 0.f, 0.f, 0.f};
  float lsum[2] = {0.f, 0.f};  // per-lane partial row-sum of |p|
  const float c1 = 0.125f * 1.44269504088896340736f;  // scale * log2(e)

  // DMA source pre-swizzle: lane writes LDS byte L=(c*4+w)*1024+lane*16
  // = row*128 + chunk*16 with row=(c*4+w)*8+(lane>>3), chunk=lane&7.
  // Stored-at-L content must be element at chunk^(row&7) = (lane&7)^(lane>>3).
  const int r8 = lane >> 3;
  const int c16s = (lane & 7) ^ r8;

  bf8a vfA[4], vfB[4];
  uint2 ebA[2][2], ebB[2][2];

  // prologue: stage 0 into Ks0, V/EB(0) into A-regs, drain
  STAGE_K(Ks0, 0)
  LOAD_VE(vfA, ebA, 0)
  __syncthreads();

  for (int kt = 0; kt < 16; kt += 2) {
    // phase A: prefetch kt+1 (DMA->Ks1, regs->B), compute kt from Ks0/A
    STAGE_K(Ks1, kt + 1)
    LOAD_VE(vfB, ebB, kt + 1)
    COMPUTE(Ks0, vfA, ebA)
    __syncthreads();  // kt+1 data landed; all waves done reading Ks0
    // phase B: prefetch kt+2 (DMA->Ks0, regs->A), compute kt+1 from Ks1/B
    if (kt < 14) {
      STAGE_K(Ks0, kt + 2)
      LOAD_VE(vfA, ebA, kt + 2)
    }
    COMPUTE(Ks1, vfB, ebB)
    __syncthreads();  // kt+2 data landed; all waves done reading Ks1
  }

  // ---------------- merge epilogue (plain sums, 2 st-passes) ----------------
  float* const Obuf = (float*)smem;             // [4][16 s][66 e]
  float* const Lbuf = (float*)(smem + 41984);   // [4][16 s]
#pragma unroll
  for (int st = 0; st < 2; ++st) {
    float ls = lsum[st];
    ls += __shfl_xor(ls, 16);
    ls += __shfl_xor(ls, 32);
    if (lane < 16) Lbuf[w * 16 + l16] = ls;
#pragma unroll
    for (int nt = 0; nt < 4; ++nt)
      *(float4a*)&Obuf[w * 1056 + l16 * 66 + nt * 16 + quad * 4] = (float4){
          oacc[st][nt][0], oacc[st][nt][1], oacc[st][nt][2], oacc[st][nt][3]};
    __syncthreads();
    // sum across waves + write: s = tid&15, e = (tid>>4)*4 + [0,4)
    {
      const int s_ = tid & 15, eg = (tid >> 4) * 4;
      float a0 = 0.f, a1 = 0.f, a2 = 0.f, a3 = 0.f;
#pragma unroll
      for (int wp = 0; wp < 4; ++wp) {
        const float4 x = *(const float4a*)&Obuf[wp * 1056 + s_ * 66 + eg];
        a0 += x.x; a1 += x.y; a2 += x.z; a3 += x.w;
      }
      const float lt = Lbuf[s_] + Lbuf[16 + s_] + Lbuf[32 + s_] + Lbuf[48 + s_];
      const float inv = 1.0f / lt;
      ushort4 o;
      o.x = f2b(a0 * inv); o.y = f2b(a1 * inv); o.z = f2b(a2 * inv); o.w = f2b(a3 * inv);
      *(ushort4a*)(Ao + ((s0 + st * 16 + s_) * 2 + bb) * 1024 + hh * 64 + eg) = o;
    }
    if (st == 0) __syncthreads();  // before pass 1 overwrites Obuf/Lbuf
  }
}

// ---------------------------------------------------------------------------
extern "C" void kernel_launch(void* const* d_in, const int* in_sizes, int n_in,
                              void* d_out, int out_size, void* d_ws, size_t ws_size,
                              hipStream_t stream) {
  const float* src = (const float*)d_in[0];
  const float* eb = (const float*)d_in[1];
  const float* wq = (const float*)d_in[2];
  const float* bq = (const float*)d_in[3];
  const float* wk = (const float*)d_in[4];
  const float* bk = (const float*)d_in[5];
  const float* wv = (const float*)d_in[6];
  const float* bv = (const float*)d_in[7];
  const float* wo = (const float*)d_in[8];
  const float* bo = (const float*)d_in[9];
  u16* ws = (u16*)d_ws;
  const size_t MM = 1024 * 1024;
  u16* wqT = ws;             // bf16 [N][K]
  u16* wkT = ws + MM;
  u16* wvT = ws + 2 * MM;
  u16* woT = ws + 3 * MM;
  u16* srcB = ws + 4 * MM;   // bf16 [4096][1024] -- dead after QKV GEMM
  u16* eb2 = ws + 4 * MM;    // bf16 tiled signed-exp EB (aliases srcB, written after)
  u16* qW = ws + 8 * MM;     // bf16 [32][2048][64]
  u16* kW = ws + 12 * MM;    // bf16 [32][2048][64]
  u16* vW = ws + 16 * MM;    // bf16 [32][64][2048] (V^T)
  u16* aO = ws + 20 * MM;    // bf16 [4096][1024]
  float* out = (float*)d_out;

  convert_src<<<dim3(4096), 256, 0, stream>>>(src, srcB);
  transpose4<<<dim3(16, 16, 4), 256, 0, stream>>>(wq, wk, wv, wo, wqT, wkT, wvT, woT);
  gemm_bt<<<dim3(8, 32, 3), 256, 0, stream>>>(srcB, wqT, wkT, wvT, bq, bk, bv,
                                              qW, kW, vW, nullptr, 0);
  prep_eb<<<dim3(4096), 256, 0, stream>>>(eb, eb2);  // after QKV GEMM (aliases srcB)
  attn_fused<<<dim3(2048), 256, 0, stream>>>(qW, kW, vW, eb2, aO);
  gemm_bt<<<dim3(8, 32, 1), 256, 0, stream>>>(aO, woT, woT, woT, bo, bo, bo,
                                              nullptr, nullptr, nullptr, out, 1);
}

// Round 5
// 259.165 us; speedup vs baseline: 1.2131x; 1.0940x over previous
//
#include <hip/hip_runtime.h>
#include <stdint.h>

typedef unsigned short u16;
typedef unsigned int u32;

typedef __bf16 bf8 __attribute__((ext_vector_type(8)));
typedef bf8 bf8a __attribute__((may_alias));
typedef float f32x4 __attribute__((ext_vector_type(4)));
typedef uint2 uint2a __attribute__((may_alias));
typedef ushort4 ushort4a __attribute__((may_alias));
typedef float4 float4a __attribute__((may_alias));

#define MFMA_BF16(a, b, c) __builtin_amdgcn_mfma_f32_16x16x32_bf16((a), (b), (c), 0, 0, 0)

__device__ __forceinline__ u16 f2b(float x) {
  u32 u = __float_as_uint(x);
  return (u16)((u + 0x7fffu + ((u >> 16) & 1u)) >> 16);  // RNE
}
__device__ __forceinline__ u32 pack2(float a, float b) {  // two f32 -> packed bf16x2 (sign-preserving)
  u32 ua = __float_as_uint(a), ub = __float_as_uint(b);
  return ((ua + 0x8000u) >> 16) | ((ub + 0x8000u) & 0xffff0000u);
}
__device__ __forceinline__ void async16(const u16* g, void* l) {
  __builtin_amdgcn_global_load_lds((const __attribute__((address_space(1))) u32*)g,
                                   (__attribute__((address_space(3))) u32*)l, 16, 0, 0);
}

// ---------------------------------------------------------------------------
// src convert: fp32 [4096][1024] -> bf16 same layout. 1 float4 per thread.
// ---------------------------------------------------------------------------
__global__ __launch_bounds__(256) void convert_src(const float* __restrict__ src,
                                                   u16* __restrict__ dst) {
  const int i = blockIdx.x * 256 + threadIdx.x;  // float4 index
  float4 v = *(const float4a*)(src + i * 4);
  ushort4 o;
  o.x = f2b(v.x); o.y = f2b(v.y); o.z = f2b(v.z); o.w = f2b(v.w);
  *(ushort4a*)(dst + i * 4) = o;
}

// ---------------------------------------------------------------------------
// EB precompute: fp32 [2048][2048] -> bf16 sign(b)*exp(b), 16x16-tiled layout:
// E2[(s>>4)*128 + (t>>4)][ (s&15)*16 + (t&15) ]  (256 elem = 512 B per tile)
// ---------------------------------------------------------------------------
__global__ __launch_bounds__(256) void prep_eb(const float* __restrict__ EB,
                                               u16* __restrict__ E2) {
  const int gid = blockIdx.x * 256 + threadIdx.x;
  const int s = gid >> 9;            // 512 float4 per row
  const int t = (gid & 511) * 4;
  const float4 v = *(const float4a*)(EB + s * 2048 + t);
  const float c2 = 1.44269504088896340736f;  // log2(e)
  ushort4 o;
  o.x = f2b(__builtin_amdgcn_exp2f(v.x * c2)) | (u16)((__float_as_uint(v.x) >> 16) & 0x8000u);
  o.y = f2b(__builtin_amdgcn_exp2f(v.y * c2)) | (u16)((__float_as_uint(v.y) >> 16) & 0x8000u);
  o.z = f2b(__builtin_amdgcn_exp2f(v.z * c2)) | (u16)((__float_as_uint(v.z) >> 16) & 0x8000u);
  o.w = f2b(__builtin_amdgcn_exp2f(v.w * c2)) | (u16)((__float_as_uint(v.w) >> 16) & 0x8000u);
  const int ti = ((s >> 4) * 128 + (t >> 4)) * 256 + (s & 15) * 16 + (t & 15);
  *(ushort4a*)(E2 + ti) = o;
}

// ---------------------------------------------------------------------------
// Weight transpose+convert: w fp32 [K=1024][N=1024] -> wT bf16 [N][K]
// ---------------------------------------------------------------------------
__global__ __launch_bounds__(256) void transpose4(
    const float* __restrict__ w0, const float* __restrict__ w1,
    const float* __restrict__ w2, const float* __restrict__ w3,
    u16* __restrict__ t0, u16* __restrict__ t1, u16* __restrict__ t2, u16* __restrict__ t3) {
  const int z = blockIdx.z;
  const float* W = z == 0 ? w0 : z == 1 ? w1 : z == 2 ? w2 : w3;
  u16* T = z == 0 ? t0 : z == 1 ? t1 : z == 2 ? t2 : t3;
  __shared__ __align__(8) u16 tile[64][68];
  const int tid = threadIdx.x;
  const int ty = tid >> 4, tx = tid & 15;
  const int kb = blockIdx.y * 64, nb = blockIdx.x * 64;
#pragma unroll
  for (int i = 0; i < 4; ++i) {
    int lk = ty + i * 16;
    float4 v = *(const float4a*)(W + (kb + lk) * 1024 + nb + tx * 4);
    ushort4 h;
    h.x = f2b(v.x); h.y = f2b(v.y); h.z = f2b(v.z); h.w = f2b(v.w);
    *(ushort4a*)&tile[lk][tx * 4] = h;
  }
  __syncthreads();
#pragma unroll
  for (int i = 0; i < 4; ++i) {
    int ln = ty + i * 16;
    ushort4 v;
    v.x = tile[tx * 4 + 0][ln];
    v.y = tile[tx * 4 + 1][ln];
    v.z = tile[tx * 4 + 2][ln];
    v.w = tile[tx * 4 + 3][ln];
    *(ushort4a*)(T + (nb + ln) * 1024 + kb + tx * 4) = v;
  }
}

// ---------------------------------------------------------------------------
// GEMM: C[M][N] = A[M,1024] * Bt[N,1024]^T + bias[n]   (m97 structure)
// ---------------------------------------------------------------------------
__global__ __launch_bounds__(256) void gemm_bt(
    const u16* __restrict__ A,
    const u16* __restrict__ B0, const u16* __restrict__ B1, const u16* __restrict__ B2,
    const float* __restrict__ c0, const float* __restrict__ c1, const float* __restrict__ c2,
    u16* __restrict__ O0, u16* __restrict__ O1, u16* __restrict__ O2,
    float* __restrict__ Of, int plain) {
  __shared__ __align__(16) u16 sm[8192];
  u16* As = sm;
  u16* Bs = sm + 4096;
  const int tid = threadIdx.x, lane = tid & 63, w = tid >> 6;
  const int wm = w >> 1, wn = w & 1, quad = lane >> 4, l16 = lane & 15;
  const int z = blockIdx.z;
  const u16* Bt = z == 0 ? B0 : (z == 1 ? B1 : B2);
  const float* bi = z == 0 ? c0 : (z == 1 ? c1 : c2);
  u16* O = z == 0 ? O0 : (z == 1 ? O1 : O2);
  const int row0 = blockIdx.y * 128, col0 = blockIdx.x * 128;

  f32x4 acc[4][4];
#pragma unroll
  for (int i = 0; i < 4; ++i)
#pragma unroll
    for (int j = 0; j < 4; ++j) acc[i][j] = f32x4{0.f, 0.f, 0.f, 0.f};

  const int e0 = tid, e1 = tid + 256;
  const int r0 = e0 >> 2, cc0 = (e0 & 3) * 8;
  const int r1 = e1 >> 2, cc1 = (e1 & 3) * 8;
  const u32 lb0 = (u32)(w * 64) * 16;
  const u32 lb1 = (u32)(w * 64 + 256) * 16;

  for (int k0 = 0; k0 < 1024; k0 += 32) {
    __syncthreads();
    async16(A + (row0 + r0) * 1024 + k0 + cc0, (char*)As + lb0);
    async16(A + (row0 + r1) * 1024 + k0 + cc1, (char*)As + lb1);
    async16(Bt + (col0 + r0) * 1024 + k0 + cc0, (char*)Bs + lb0);
    async16(Bt + (col0 + r1) * 1024 + k0 + cc1, (char*)Bs + lb1);
    __syncthreads();
    bf8a af[4], bfr[4];
#pragma unroll
    for (int i = 0; i < 4; ++i) {
      af[i] = *(const bf8a*)(As + (wm * 64 + i * 16 + l16) * 32 + quad * 8);
      bfr[i] = *(const bf8a*)(Bs + (wn * 64 + i * 16 + l16) * 32 + quad * 8);
    }
#pragma unroll
    for (int mt = 0; mt < 4; ++mt)
#pragma unroll
      for (int nt = 0; nt < 4; ++nt) acc[mt][nt] = MFMA_BF16(af[mt], bfr[nt], acc[mt][nt]);
  }

#pragma unroll
  for (int nt = 0; nt < 4; ++nt) {
    const int col = col0 + wn * 64 + nt * 16 + l16;
    const float bcol = bi[col];
#pragma unroll
    for (int mt = 0; mt < 4; ++mt) {
#pragma unroll
      for (int r = 0; r < 4; ++r) {
        const int rm = row0 + wm * 64 + mt * 16 + quad * 4 + r;
        const float fv = acc[mt][nt][r] + bcol;
        if (plain) {
          Of[rm * 1024 + col] = fv;
        } else {
          const u16 hv = f2b(fv);
          const int s = rm >> 1, b_ = rm & 1, hh = col >> 6, e = col & 63;
          const int p = b_ * 16 + hh;
          if (z < 2) O[(p * 2048 + s) * 64 + e] = hv;  // [pair][s][64]
          else O[(p * 64 + e) * 2048 + s] = hv;        // [pair][e][s] (V^T)
        }
      }
    }
  }
}

// ---------------------------------------------------------------------------
// Flash attention v13 = v12 structure with QBLK 32 -> 64 (st: 2 -> 4).
// Rationale: v12 proved the 2-phase prefetch holds registers (VGPR 84) but
// gained only 3us -- one ~650cy compute phase can't cover ~1700+cy of load
// latency+queueing, and TLP is capped ~2.4 blocks. Doubling the Q-tile:
//   - halves K/V L2 traffic + halves block count (per-CU L2-BW floor 39->23us)
//   - doubles compute per iteration (~1300cy) so the same depth-1 prefetch
//     covers most of the latency
//   - VGPR cost: qf 32, oacc 64, eb dbuf 32 -> ~200, 2 waves/SIMD (bounds 256,2)
// V stays JIT at compute-top (consumed at the end, self-covering); EB is
// register-double-buffered; K keeps the LDS double-buffer + XOR swizzle.
// XCD pinning kept: grid 1024 = 8 xcd * 4 pair * 32 qt.
// ---------------------------------------------------------------------------
#define STAGE_K(Ksbuf, kt_)                                                         \
  {                                                                                 \
    _Pragma("unroll") for (int c = 0; c < 4; ++c) {                                 \
      const int row_ = c * 32 + w * 8 + r8;                                         \
      async16(Kp + ((kt_) * 128 + row_) * 64 + c16s * 8,                            \
              (char*)(Ksbuf) + (c * 4 + w) * 1024);                                 \
    }                                                                               \
  }

#define LOAD_E(eb, kt_)                                                             \
  {                                                                                 \
    const int tb16_ = (kt_) * 8 + w * 2;                                            \
    _Pragma("unroll") for (int st = 0; st < 4; ++st)                                \
      _Pragma("unroll") for (int tt = 0; tt < 2; ++tt)                              \
        eb[st][tt] = *(const uint2a*)(EBp + ((qt * 4 + st) * 128 + tb16_ + tt) * 256 \
                                      + l16 * 16 + quad * 4);                       \
  }

#define COMPUTE(Ksbuf, eb, kt_)                                                     \
  {                                                                                 \
    const int tb_ = (kt_) * 128 + w * 32;                                           \
    bf8a vf[4]; /* V^T JIT: rows e, k = t strip; consumed ~800cy later */           \
    _Pragma("unroll") for (int nt = 0; nt < 4; ++nt)                                \
      vf[nt] = *(const bf8a*)(Vp + (nt * 16 + l16) * 2048 + tb_ + quad * 8);        \
    bf8a kf[2][2];                                                                  \
    _Pragma("unroll") for (int tt = 0; tt < 2; ++tt) {                              \
      const int row_ = w * 32 + tt * 16 + l16; /* row_&7 == l16&7 */                \
      _Pragma("unroll") for (int ks = 0; ks < 2; ++ks) {                            \
        const int cc_ = ((ks * 4 + quad) ^ (l16 & 7)) * 8;                          \
        kf[tt][ks] = *(const bf8a*)((Ksbuf) + row_ * 64 + cc_);                     \
      }                                                                             \
    }                                                                               \
    f32x4 sacc[4][2]; /* [st][tt] */                                                \
    __builtin_amdgcn_s_setprio(1);                                                  \
    _Pragma("unroll") for (int tt = 0; tt < 2; ++tt)                                \
      _Pragma("unroll") for (int st = 0; st < 4; ++st) {                            \
        f32x4 t0_ = f32x4{0.f, 0.f, 0.f, 0.f};                                      \
        t0_ = MFMA_BF16(kf[tt][0], qf[st][0], t0_);                                 \
        sacc[st][tt] = MFMA_BF16(kf[tt][1], qf[st][1], t0_);                        \
      }                                                                             \
    __builtin_amdgcn_s_setprio(0);                                                  \
    _Pragma("unroll") for (int st = 0; st < 4; ++st) {                              \
      _Pragma("unroll") for (int tt = 0; tt < 2; ++tt) {                            \
        const uint2 e_ = eb[st][tt];                                                \
        const float g0 = __uint_as_float(e_.x << 16);                               \
        const float g1 = __uint_as_float(e_.x & 0xffff0000u);                       \
        const float g2 = __uint_as_float(e_.y << 16);                               \
        const float g3 = __uint_as_float(e_.y & 0xffff0000u);                       \
        const float p0 = __builtin_amdgcn_exp2f(sacc[st][tt][0] * c1) * g0;         \
        const float p1 = __builtin_amdgcn_exp2f(sacc[st][tt][1] * c1) * g1;         \
        const float p2 = __builtin_amdgcn_exp2f(sacc[st][tt][2] * c1) * g2;         \
        const float p3 = __builtin_amdgcn_exp2f(sacc[st][tt][3] * c1) * g3;         \
        lsum[st] += (__builtin_fabsf(p0) + __builtin_fabsf(p1)) +                   \
                    (__builtin_fabsf(p2) + __builtin_fabsf(p3));                    \
        uint2 v_;                                                                   \
        v_.x = pack2(p0, p1);                                                       \
        v_.y = pack2(p2, p3);                                                       \
        *(uint2a*)(Pw + st * 1152 + l16 * 72 + tt * 32 + quad * 8) = v_;            \
      }                                                                             \
    }                                                                               \
    _Pragma("unroll") for (int st = 0; st < 4; ++st) {                              \
      bf8a pf = *(const bf8a*)(Pw + st * 1152 + l16 * 72 + quad * 16);              \
      __builtin_amdgcn_s_setprio(1);                                                \
      _Pragma("unroll") for (int nt = 0; nt < 4; ++nt)                              \
        oacc[st][nt] = MFMA_BF16(vf[nt], pf, oacc[st][nt]);                         \
      __builtin_amdgcn_s_setprio(0);                                                \
    }                                                                               \
  }

__global__ __launch_bounds__(256, 2) void attn_fused(
    const u16* __restrict__ Qw, const u16* __restrict__ Kw, const u16* __restrict__ Vw,
    const u16* __restrict__ EBp, u16* __restrict__ Ao) {
  // LDS map: [0,16384) Ks0, [16384,32768) Ks1  (K tile [128 t][64 d] bf16,
  //            XOR-swizzled rows, double-buffered);
  //          [32768,51200) per-wave P tiles [4][4 st][16 s][36 t] u16;
  //          [51200,51456) Lbuf float[4][16].
  // Epilogue: Obuf float[4][16][66] (16896 B) aliases [0,16896) after sync.
  __shared__ __align__(16) char smem[51456];
  u16* const Ks0 = (u16*)smem;
  u16* const Ks1 = (u16*)(smem + 16384);
  const int tid = threadIdx.x, lane = tid & 63, w = tid >> 6;
  const int quad = lane >> 4, l16 = lane & 15;
  const int id = blockIdx.x;
  const int xcd = id & 7, idx = id >> 3;
  const int pair = xcd * 4 + (idx & 3);  // pair fast: 4 pairs pinned per XCD
  const int qt = idx >> 2;               // qt slow (0..31): 64 q-rows per block
  const int bb = pair >> 4, hh = pair & 15;
  const u16* Qp = Qw + pair * (2048 * 64);
  const u16* Kp = Kw + pair * (2048 * 64);
  const u16* Vp = Vw + pair * (64 * 2048);
  const int s0 = qt * 64;  // block's 64 q-rows (shared by all waves)
  char* const Pw = smem + 32768 + w * 4608;  // [4 st][16 s][36 t] u16 (pad 36)

  bf8a qf[4][2];  // B-operand (Q^T): [st][ks]; n=s, k=d
#pragma unroll
  for (int st = 0; st < 4; ++st)
#pragma unroll
    for (int ks = 0; ks < 2; ++ks)
      qf[st][ks] = *(const bf8a*)(Qp + (s0 + st * 16 + l16) * 64 + ks * 32 + quad * 8);

  f32x4 oacc[4][4];  // O^T partial: [st][nt]; e = nt*16+quad*4+r, s = st*16+l16
#pragma unroll
  for (int i = 0; i < 4; ++i)
#pragma unroll
    for (int j = 0; j < 4; ++j) oacc[i][j] = f32x4{0.f, 0.f, 0.f, 0.f};
  float lsum[4] = {0.f, 0.f, 0.f, 0.f};  // per-lane partial row-sum of |p|
  const float c1 = 0.125f * 1.44269504088896340736f;  // scale * log2(e)

  // DMA source pre-swizzle: lane writes LDS byte L=(c*4+w)*1024+lane*16
  // = row*128 + chunk*16 with row=(c*4+w)*8+(lane>>3), chunk=lane&7.
  // Stored-at-L content must be element at chunk^(row&7) = (lane&7)^(lane>>3).
  const int r8 = lane >> 3;
  const int c16s = (lane & 7) ^ r8;

  uint2 ebA[4][2], ebB[4][2];

  // prologue: stage 0 into Ks0, EB(0) into A-regs, drain
  STAGE_K(Ks0, 0)
  LOAD_E(ebA, 0)
  __syncthreads();

  for (int kt = 0; kt < 16; kt += 2) {
    // phase A: prefetch kt+1 (DMA->Ks1, EB->B), compute kt from Ks0/A
    STAGE_K(Ks1, kt + 1)
    LOAD_E(ebB, kt + 1)
    COMPUTE(Ks0, ebA, kt)
    __syncthreads();  // kt+1 data landed; all waves done reading Ks0
    // phase B: prefetch kt+2 (DMA->Ks0, EB->A), compute kt+1 from Ks1/B
    if (kt < 14) {
      STAGE_K(Ks0, kt + 2)
      LOAD_E(ebA, kt + 2)
    }
    COMPUTE(Ks1, ebB, kt + 1)
    __syncthreads();  // kt+2 data landed; all waves done reading Ks1
  }

  // ---------------- merge epilogue (plain sums, 4 st-passes) ----------------
  float* const Obuf = (float*)smem;             // [4][16 s][66 e]
  float* const Lbuf = (float*)(smem + 51200);   // [4][16 s]
#pragma unroll
  for (int st = 0; st < 4; ++st) {
    float ls = lsum[st];
    ls += __shfl_xor(ls, 16);
    ls += __shfl_xor(ls, 32);
    if (lane < 16) Lbuf[w * 16 + l16] = ls;
#pragma unroll
    for (int nt = 0; nt < 4; ++nt)
      *(float4a*)&Obuf[w * 1056 + l16 * 66 + nt * 16 + quad * 4] = (float4){
          oacc[st][nt][0], oacc[st][nt][1], oacc[st][nt][2], oacc[st][nt][3]};
    __syncthreads();
    // sum across waves + write: s = tid&15, e = (tid>>4)*4 + [0,4)
    {
      const int s_ = tid & 15, eg = (tid >> 4) * 4;
      float a0 = 0.f, a1 = 0.f, a2 = 0.f, a3 = 0.f;
#pragma unroll
      for (int wp = 0; wp < 4; ++wp) {
        const float4 x = *(const float4a*)&Obuf[wp * 1056 + s_ * 66 + eg];
        a0 += x.x; a1 += x.y; a2 += x.z; a3 += x.w;
      }
      const float lt = Lbuf[s_] + Lbuf[16 + s_] + Lbuf[32 + s_] + Lbuf[48 + s_];
      const float inv = 1.0f / lt;
      ushort4 o;
      o.x = f2b(a0 * inv); o.y = f2b(a1 * inv); o.z = f2b(a2 * inv); o.w = f2b(a3 * inv);
      *(ushort4a*)(Ao + ((s0 + st * 16 + s_) * 2 + bb) * 1024 + hh * 64 + eg) = o;
    }
    if (st < 3) __syncthreads();  // before next pass overwrites Obuf/Lbuf
  }
}

// ---------------------------------------------------------------------------
extern "C" void kernel_launch(void* const* d_in, const int* in_sizes, int n_in,
                              void* d_out, int out_size, void* d_ws, size_t ws_size,
                              hipStream_t stream) {
  const float* src = (const float*)d_in[0];
  const float* eb = (const float*)d_in[1];
  const float* wq = (const float*)d_in[2];
  const float* bq = (const float*)d_in[3];
  const float* wk = (const float*)d_in[4];
  const float* bk = (const float*)d_in[5];
  const float* wv = (const float*)d_in[6];
  const float* bv = (const float*)d_in[7];
  const float* wo = (const float*)d_in[8];
  const float* bo = (const float*)d_in[9];
  u16* ws = (u16*)d_ws;
  const size_t MM = 1024 * 1024;
  u16* wqT = ws;             // bf16 [N][K]
  u16* wkT = ws + MM;
  u16* wvT = ws + 2 * MM;
  u16* woT = ws + 3 * MM;
  u16* srcB = ws + 4 * MM;   // bf16 [4096][1024] -- dead after QKV GEMM
  u16* eb2 = ws + 4 * MM;    // bf16 tiled signed-exp EB (aliases srcB, written after)
  u16* qW = ws + 8 * MM;     // bf16 [32][2048][64]
  u16* kW = ws + 12 * MM;    // bf16 [32][2048][64]
  u16* vW = ws + 16 * MM;    // bf16 [32][64][2048] (V^T)
  u16* aO = ws + 20 * MM;    // bf16 [4096][1024]
  float* out = (float*)d_out;

  convert_src<<<dim3(4096), 256, 0, stream>>>(src, srcB);
  transpose4<<<dim3(16, 16, 4), 256, 0, stream>>>(wq, wk, wv, wo, wqT, wkT, wvT, woT);
  gemm_bt<<<dim3(8, 32, 3), 256, 0, stream>>>(srcB, wqT, wkT, wvT, bq, bk, bv,
                                              qW, kW, vW, nullptr, 0);
  prep_eb<<<dim3(4096), 256, 0, stream>>>(eb, eb2);  // after QKV GEMM (aliases srcB)
  attn_fused<<<dim3(1024), 256, 0, stream>>>(qW, kW, vW, eb2, aO);
  gemm_bt<<<dim3(8, 32, 1), 256, 0, stream>>>(aO, woT, woT, woT, bo, bo, bo,
                                              nullptr, nullptr, nullptr, out, 1);
}